// Round 3
// baseline (204.862 us; speedup 1.0000x reference)
//
#include <hip/hip_runtime.h>

#define EPSV 1e-5f

__device__ __forceinline__ float sigmoidf_(float z) {
    return 1.0f / (1.0f + __expf(-z));
}

// ---------------------------------------------------------------------------
// Pass 1: per-(b,g) stats. One block per (b,g); 512 threads.
// tid = cc*8 + ts : 8 threads per channel, each reads 24(+1) float4 of the
// 196-float4 channel row. Per-channel sum via 8-lane shfl_xor; group mu/var
// for the x1 half via wave + LDS combine.
// ws layout per bg (34 floats): [0..31]=a0 gate (sigmoid already applied),
// [32]=mu, [33]=rstd.
// ---------------------------------------------------------------------------
__global__ __launch_bounds__(512, 4) void stats_kernel(
    const float4* __restrict__ x4,
    const float* __restrict__ cweight,
    const float* __restrict__ cbias,
    float* __restrict__ ws)
{
    const int bg  = blockIdx.x;
    const int tid = threadIdx.x;
    const int cc  = tid >> 3;     // 0..63
    const int ts  = tid & 7;      // 0..7

    const float4* __restrict__ xch = x4 + (size_t)bg * (64 * 196) + cc * 196;

    float s = 0.f, ss = 0.f;
#pragma unroll
    for (int k = 0; k < 24; ++k) {
        float4 v = xch[ts + 8 * k];
        s  += (v.x + v.y) + (v.z + v.w);
        ss += (v.x * v.x + v.y * v.y) + (v.z * v.z + v.w * v.w);
    }
    if (ts < 4) {                 // 196 = 8*24 + 4 remainder
        float4 v = xch[192 + ts];
        s  += (v.x + v.y) + (v.z + v.w);
        ss += (v.x * v.x + v.y * v.y) + (v.z * v.z + v.w * v.w);
    }

    // 8-lane cluster reduce -> per-channel sums
    s  += __shfl_xor(s, 1, 64);  s  += __shfl_xor(s, 2, 64);  s  += __shfl_xor(s, 4, 64);
    ss += __shfl_xor(ss, 1, 64); ss += __shfl_xor(ss, 2, 64); ss += __shfl_xor(ss, 4, 64);

    __shared__ float lds_s[4];
    __shared__ float lds_ss[4];

    if (cc < 32) {
        // channel-gate half: only the mean is needed; fold sigmoid here
        if (ts == 0) {
            const float mean = s * (1.0f / 784.0f);
            ws[(size_t)bg * 34 + cc] = sigmoidf_(cweight[cc] * mean + cbias[cc]);
        }
    } else {
        // group-norm half: continue to full-wave sums (waves 4..7)
        s  += __shfl_xor(s, 8, 64);  s  += __shfl_xor(s, 16, 64);  s  += __shfl_xor(s, 32, 64);
        ss += __shfl_xor(ss, 8, 64); ss += __shfl_xor(ss, 16, 64); ss += __shfl_xor(ss, 32, 64);
        const int w = (tid >> 6) - 4;     // 0..3
        if ((tid & 63) == 0) { lds_s[w] = s; lds_ss[w] = ss; }
    }
    __syncthreads();
    if (tid == 0) {
        const float S  = (lds_s[0] + lds_s[1]) + (lds_s[2] + lds_s[3]);
        const float SS = (lds_ss[0] + lds_ss[1]) + (lds_ss[2] + lds_ss[3]);
        constexpr float inv_n = 1.0f / (32.0f * 784.0f);
        const float mu   = S * inv_n;
        const float var  = SS * inv_n - mu * mu;
        const float rstd = rsqrtf(fmaxf(var, 0.f) + EPSV);
        ws[(size_t)bg * 34 + 32] = mu;
        ws[(size_t)bg * 34 + 33] = rstd;
    }
}

// ---------------------------------------------------------------------------
// Pass 2: pure streaming apply. Grid-stride over float4 elements; no barriers,
// no cross-lane ops. x is L3-resident from pass 1; output channel-interleaved.
// ---------------------------------------------------------------------------
__global__ __launch_bounds__(256, 8) void apply_kernel(
    const float4* __restrict__ x4,
    const float* __restrict__ sweight,
    const float* __restrict__ sbias,
    const float* __restrict__ ws,
    float4* __restrict__ out4,
    int total4)
{
    for (int i = blockIdx.x * 256 + threadIdx.x; i < total4;
         i += gridDim.x * 256) {
        const int bg  = i / 12544;            // 64 ch * 196 f4
        const int rem = i - bg * 12544;
        const int cc  = rem / 196;
        const int p   = rem - cc * 196;

        const float4 v = x4[i];
        float4 r;
        if (cc < 32) {
            const float a0 = ws[(size_t)bg * 34 + cc];
            r.x = v.x * a0; r.y = v.y * a0; r.z = v.z * a0; r.w = v.w * a0;
        } else {
            const float mu   = ws[(size_t)bg * 34 + 32];
            const float rstd = ws[(size_t)bg * 34 + 33];
            const float w    = sweight[cc - 32];
            const float bch  = sbias[cc - 32];
            r.x = v.x * sigmoidf_(w * ((v.x - mu) * rstd) + bch);
            r.y = v.y * sigmoidf_(w * ((v.y - mu) * rstd) + bch);
            r.z = v.z * sigmoidf_(w * ((v.z - mu) * rstd) + bch);
            r.w = v.w * sigmoidf_(w * ((v.w - mu) * rstd) + bch);
        }

        // output channel interleave: c = g*64+cc -> cp = 2*(c%256) + c/256
        const int b  = bg >> 3;
        const int g  = bg & 7;
        const int c  = g * 64 + cc;
        const int cp = (c < 256) ? (2 * c) : (2 * (c - 256) + 1);
        out4[(size_t)b * 100352 + (size_t)cp * 196 + p] = r;
    }
}

extern "C" void kernel_launch(void* const* d_in, const int* in_sizes, int n_in,
                              void* d_out, int out_size, void* d_ws, size_t ws_size,
                              hipStream_t stream) {
    const float* x  = (const float*)d_in[0];
    const float* cw = (const float*)d_in[1];
    const float* cb = (const float*)d_in[2];
    const float* sw = (const float*)d_in[3];
    const float* sb = (const float*)d_in[4];
    float* out = (float*)d_out;
    float* ws  = (float*)d_ws;

    const int B = in_sizes[0] / (512 * 784);
    const int nbg = B * 8;                       // 512 groups
    const int total4 = B * 512 * 196;            // float4 count

    stats_kernel<<<nbg, 512, 0, stream>>>(
        (const float4*)x, cw, cb, ws);

    const int apply_blocks = 2048;
    apply_kernel<<<apply_blocks, 256, 0, stream>>>(
        (const float4*)x, sw, sb, ws, (float4*)out, total4);
}

// Round 6
// 199.907 us; speedup vs baseline: 1.0248x; 1.0248x over previous
//
#include <hip/hip_runtime.h>

typedef float f32x4 __attribute__((ext_vector_type(4)));
typedef float f32x2 __attribute__((ext_vector_type(2)));

#define EPSV 1e-5f

__device__ __forceinline__ float sigmoidf_(float z) {
    return 1.0f / (1.0f + __expf(-z));
}

// ---------------------------------------------------------------------------
// Dispatch 1. Two block families in one launch:
//   blocks [0, nA):        x0-half gate — ONE WAVE PER CHANNEL, barrier-free.
//                          wave loads its 196 float4, shfl-reduces the mean,
//                          gates, nt-stores. One read + one write, no LDS.
//   blocks [nA, nA+nB):    x1-half stats — one block per (b,g); reduces the
//                          contiguous 6272-float4 x1 slab to mu/rstd, writes
//                          per-channel affine (A,B): arg = A*v + B.
// ---------------------------------------------------------------------------
__global__ __launch_bounds__(256) void gate_stats_kernel(
    const f32x4* __restrict__ x4,
    const float* __restrict__ cweight,
    const float* __restrict__ cbias,
    const float* __restrict__ sweight,
    const float* __restrict__ sbias,
    f32x4* __restrict__ out4,
    f32x2* __restrict__ wsAB,      // [bg][32] (A,B) pairs
    int nA)
{
    if ((int)blockIdx.x < nA) {
        // ---------- x0 half: wave-per-channel ----------
        const int w  = blockIdx.x * 4 + (threadIdx.x >> 6); // global x0-channel
        const int ln = threadIdx.x & 63;
        const int bg = w >> 5;          // 32 x0-channels per (b,g)
        const int cc = w & 31;

        const f32x4* __restrict__ xch = x4 + (size_t)bg * 12544 + cc * 196;
        f32x4 v0 = xch[ln];
        f32x4 v1 = xch[64 + ln];
        f32x4 v2 = xch[128 + ln];
        f32x4 v3 = {0.f, 0.f, 0.f, 0.f};
        const bool extra = (ln < 4);
        if (extra) v3 = xch[192 + ln];

        float s = (v0.x + v0.y) + (v0.z + v0.w)
                + (v1.x + v1.y) + (v1.z + v1.w)
                + (v2.x + v2.y) + (v2.z + v2.w)
                + (v3.x + v3.y) + (v3.z + v3.w);
#pragma unroll
        for (int m = 32; m >= 1; m >>= 1) s += __shfl_xor(s, m, 64);

        const float a0 = sigmoidf_(cweight[cc] * (s * (1.0f / 784.0f)) + cbias[cc]);

        const int b = bg >> 3, g = bg & 7;
        const int c  = g * 64 + cc;
        const int cp = (c < 256) ? (2 * c) : (2 * (c - 256) + 1);
        f32x4* __restrict__ och = out4 + (size_t)b * 100352 + (size_t)cp * 196;

        __builtin_nontemporal_store(v0 * a0, &och[ln]);
        __builtin_nontemporal_store(v1 * a0, &och[64 + ln]);
        __builtin_nontemporal_store(v2 * a0, &och[128 + ln]);
        if (extra) __builtin_nontemporal_store(v3 * a0, &och[192 + ln]);
    } else {
        // ---------- x1 half: group stats ----------
        const int bg  = (int)blockIdx.x - nA;
        const int tid = threadIdx.x;
        // x1 slab: contiguous 6272 float4 at offset 6272 within the group
        const f32x4* __restrict__ xs = x4 + (size_t)bg * 12544 + 6272;

        float s = 0.f, ss = 0.f;
#pragma unroll
        for (int k = 0; k < 24; ++k) {
            f32x4 v = xs[tid + 256 * k];
            s  += (v.x + v.y) + (v.z + v.w);
            ss += (v.x * v.x + v.y * v.y) + (v.z * v.z + v.w * v.w);
        }
        if (tid < 128) {                       // 6272 = 256*24 + 128
            f32x4 v = xs[6144 + tid];
            s  += (v.x + v.y) + (v.z + v.w);
            ss += (v.x * v.x + v.y * v.y) + (v.z * v.z + v.w * v.w);
        }

#pragma unroll
        for (int m = 32; m >= 1; m >>= 1) {
            s  += __shfl_xor(s,  m, 64);
            ss += __shfl_xor(ss, m, 64);
        }

        __shared__ float lds_s[4], lds_ss[4], lds_st[2];
        const int wv = tid >> 6;
        if ((tid & 63) == 0) { lds_s[wv] = s; lds_ss[wv] = ss; }
        __syncthreads();
        if (tid == 0) {
            const float S  = (lds_s[0] + lds_s[1]) + (lds_s[2] + lds_s[3]);
            const float SS = (lds_ss[0] + lds_ss[1]) + (lds_ss[2] + lds_ss[3]);
            constexpr float inv_n = 1.0f / (32.0f * 784.0f);
            const float mu   = S * inv_n;
            const float var  = SS * inv_n - mu * mu;
            const float rstd = rsqrtf(fmaxf(var, 0.f) + EPSV);
            lds_st[0] = mu; lds_st[1] = rstd;
        }
        __syncthreads();
        if (tid < 32) {
            const float mu = lds_st[0], rstd = lds_st[1];
            const float A  = sweight[tid] * rstd;
            f32x2 ab; ab.x = A; ab.y = sbias[tid] - A * mu;
            wsAB[bg * 32 + tid] = ab;
        }
    }
}

// ---------------------------------------------------------------------------
// Dispatch 2: x1-half apply. Pure grid-stride stream over the 51.4 MB x1 data
// (L3-hot from dispatch 1); per-channel affine -> sigmoid gate; nt store.
// ---------------------------------------------------------------------------
__global__ __launch_bounds__(256) void apply1_kernel(
    const f32x4* __restrict__ x4,
    const f32x2* __restrict__ wsAB,
    f32x4* __restrict__ out4,
    int total)                               // B*8*6272
{
    for (int i = blockIdx.x * 256 + threadIdx.x; i < total;
         i += gridDim.x * 256) {
        const int bg  = i / 6272;
        const int rem = i - bg * 6272;
        const int c1  = rem / 196;           // 0..31
        const int p   = rem - c1 * 196;

        const f32x4 v = x4[(size_t)bg * 12544 + 6272 + rem];
        const f32x2 ab = wsAB[bg * 32 + c1];

        f32x4 r;
        r.x = v.x * sigmoidf_(ab.x * v.x + ab.y);
        r.y = v.y * sigmoidf_(ab.x * v.y + ab.y);
        r.z = v.z * sigmoidf_(ab.x * v.z + ab.y);
        r.w = v.w * sigmoidf_(ab.x * v.w + ab.y);

        const int b = bg >> 3, g = bg & 7;
        const int c  = g * 64 + 32 + c1;
        const int cp = (c < 256) ? (2 * c) : (2 * (c - 256) + 1);
        __builtin_nontemporal_store(
            r, out4 + (size_t)b * 100352 + (size_t)cp * 196 + p);
    }
}

extern "C" void kernel_launch(void* const* d_in, const int* in_sizes, int n_in,
                              void* d_out, int out_size, void* d_ws, size_t ws_size,
                              hipStream_t stream) {
    const float* x  = (const float*)d_in[0];
    const float* cw = (const float*)d_in[1];
    const float* cb = (const float*)d_in[2];
    const float* sw = (const float*)d_in[3];
    const float* sb = (const float*)d_in[4];
    float* out = (float*)d_out;

    const int B  = in_sizes[0] / (512 * 784);
    const int nA = B * 64;        // x0: B*8*32 channels, 4 waves/block
    const int nB = B * 8;         // one stats block per (b,g)

    gate_stats_kernel<<<nA + nB, 256, 0, stream>>>(
        (const f32x4*)x, cw, cb, sw, sb,
        (f32x4*)out, (f32x2*)d_ws, nA);

    const int total1 = B * 8 * 6272;
    apply1_kernel<<<2048, 256, 0, stream>>>(
        (const f32x4*)x, (const f32x2*)d_ws, (f32x4*)out, total1);
}

// Round 8
// 193.880 us; speedup vs baseline: 1.0566x; 1.0311x over previous
//
#include <hip/hip_runtime.h>

typedef float f32x4 __attribute__((ext_vector_type(4)));

#define EPSV 1e-5f

__device__ __forceinline__ float sigmoidf_(float z) {
    return 1.0f / (1.0f + __expf(-z));
}

// ---------------------------------------------------------------------------
// ONE dispatch, two block families (1024 threads each):
//
//   blocks [0, nX1):   x1 half, one block per (b,g). Each thread stages
//                      6-7 float4 of the contiguous 6272-f4 x1 slab in
//                      REGISTERS (~28 VGPR), contributes to group mu/var via
//                      wave shfl + tiny LDS, barrier, then gates from regs
//                      (post-barrier = pure VALU + nt-store, no loads).
//
//   blocks [nX1, ...): x0 half, wave-per-channel (16 waves/block),
//                      completely barrier-free: load 196 f4, shfl-reduce
//                      mean, sigmoid gate, nt-store.
//
// Exactly one global read + one global write of the tensor, no workspace.
// ---------------------------------------------------------------------------
__global__ __launch_bounds__(1024, 4) void fused_sgate_onepass(
    const f32x4* __restrict__ x4,
    const float* __restrict__ cweight,
    const float* __restrict__ cbias,
    const float* __restrict__ sweight,
    const float* __restrict__ sbias,
    f32x4* __restrict__ out4,
    int nX1)
{
    const int tid = threadIdx.x;

    if ((int)blockIdx.x < nX1) {
        // ================= x1 family: one group per block =================
        const int bg = blockIdx.x;
        const int b  = bg >> 3, g = bg & 7;
        const f32x4* __restrict__ xs = x4 + (size_t)bg * 12544 + 6272;

        // stage 6272 f4 across 1024 threads: 6 each + first 128 take one more
        f32x4 w[6];
#pragma unroll
        for (int k = 0; k < 6; ++k) w[k] = xs[tid + 1024 * k];
        const bool x1e = (tid < 128);
        f32x4 we = {0.f, 0.f, 0.f, 0.f};
        if (x1e) we = xs[6144 + tid];

        // partial sums for group stats
        float s = 0.f, ss = 0.f;
#pragma unroll
        for (int k = 0; k < 6; ++k) {
            s  += (w[k].x + w[k].y) + (w[k].z + w[k].w);
            ss += (w[k].x * w[k].x + w[k].y * w[k].y)
                + (w[k].z * w[k].z + w[k].w * w[k].w);
        }
        s  += (we.x + we.y) + (we.z + we.w);
        ss += (we.x * we.x + we.y * we.y) + (we.z * we.z + we.w * we.w);

#pragma unroll
        for (int m = 32; m >= 1; m >>= 1) {
            s  += __shfl_xor(s,  m, 64);
            ss += __shfl_xor(ss, m, 64);
        }

        __shared__ float lds_s[16], lds_ss[16];
        __shared__ float ldsA[32], ldsB[32];
        if ((tid & 63) == 0) { lds_s[tid >> 6] = s; lds_ss[tid >> 6] = ss; }
        __syncthreads();

        if (tid < 32) {
            float S = 0.f, SS = 0.f;
#pragma unroll
            for (int i = 0; i < 16; ++i) { S += lds_s[i]; SS += lds_ss[i]; }
            constexpr float inv_n = 1.0f / (32.0f * 784.0f);
            const float mu   = S * inv_n;
            const float var  = SS * inv_n - mu * mu;
            const float rstd = rsqrtf(fmaxf(var, 0.f) + EPSV);
            const float A    = sweight[tid] * rstd;
            ldsA[tid] = A;
            ldsB[tid] = sbias[tid] - A * mu;
        }
        __syncthreads();

        // pin staged values live across the barrier (prevent DCE/remat games)
#pragma unroll
        for (int k = 0; k < 6; ++k)
            asm volatile("" : "+v"(w[k].x), "+v"(w[k].y),
                              "+v"(w[k].z), "+v"(w[k].w));

        // apply: arg = A*v + B, y = v * sigmoid(arg); all from regs/LDS
        f32x4* __restrict__ ob = out4 + (size_t)b * 100352;
#pragma unroll
        for (int k = 0; k < 6; ++k) {
            const int idx = tid + 1024 * k;
            const int c1  = idx / 196;
            const int p   = idx - c1 * 196;
            const float A = ldsA[c1], Bq = ldsB[c1];
            f32x4 t = w[k], r;
            r.x = t.x * sigmoidf_(A * t.x + Bq);
            r.y = t.y * sigmoidf_(A * t.y + Bq);
            r.z = t.z * sigmoidf_(A * t.z + Bq);
            r.w = t.w * sigmoidf_(A * t.w + Bq);
            const int c  = g * 64 + 32 + c1;
            const int cp = (c < 256) ? (2 * c) : (2 * (c - 256) + 1);
            __builtin_nontemporal_store(r, ob + (size_t)cp * 196 + p);
        }
        if (x1e) {
            const int idx = 6144 + tid;
            const int c1  = idx / 196;
            const int p   = idx - c1 * 196;
            const float A = ldsA[c1], Bq = ldsB[c1];
            f32x4 t = we, r;
            r.x = t.x * sigmoidf_(A * t.x + Bq);
            r.y = t.y * sigmoidf_(A * t.y + Bq);
            r.z = t.z * sigmoidf_(A * t.z + Bq);
            r.w = t.w * sigmoidf_(A * t.w + Bq);
            const int c  = g * 64 + 32 + c1;
            const int cp = (c < 256) ? (2 * c) : (2 * (c - 256) + 1);
            __builtin_nontemporal_store(r, ob + (size_t)cp * 196 + p);
        }
    } else {
        // ================= x0 family: wave-per-channel, barrier-free =======
        const int chw = ((int)blockIdx.x - nX1) * 16 + (tid >> 6);
        const int ln  = tid & 63;
        const int bg  = chw >> 5;          // 32 x0-channels per group
        const int cc  = chw & 31;

        const f32x4* __restrict__ xch = x4 + (size_t)bg * 12544 + cc * 196;
        f32x4 v0 = xch[ln];
        f32x4 v1 = xch[64 + ln];
        f32x4 v2 = xch[128 + ln];
        const bool extra = (ln < 4);
        f32x4 v3 = {0.f, 0.f, 0.f, 0.f};
        if (extra) v3 = xch[192 + ln];

        float s = (v0.x + v0.y) + (v0.z + v0.w)
                + (v1.x + v1.y) + (v1.z + v1.w)
                + (v2.x + v2.y) + (v2.z + v2.w)
                + (v3.x + v3.y) + (v3.z + v3.w);
#pragma unroll
        for (int m = 32; m >= 1; m >>= 1) s += __shfl_xor(s, m, 64);

        const float a0 = sigmoidf_(cweight[cc] * (s * (1.0f / 784.0f)) + cbias[cc]);

        const int b = bg >> 3, g = bg & 7;
        const int c  = g * 64 + cc;
        const int cp = (c < 256) ? (2 * c) : (2 * (c - 256) + 1);
        f32x4* __restrict__ och = out4 + (size_t)b * 100352 + (size_t)cp * 196;

        __builtin_nontemporal_store(v0 * a0, &och[ln]);
        __builtin_nontemporal_store(v1 * a0, &och[64 + ln]);
        __builtin_nontemporal_store(v2 * a0, &och[128 + ln]);
        if (extra) __builtin_nontemporal_store(v3 * a0, &och[192 + ln]);
    }
}

extern "C" void kernel_launch(void* const* d_in, const int* in_sizes, int n_in,
                              void* d_out, int out_size, void* d_ws, size_t ws_size,
                              hipStream_t stream) {
    const float* x  = (const float*)d_in[0];
    const float* cw = (const float*)d_in[1];
    const float* cb = (const float*)d_in[2];
    const float* sw = (const float*)d_in[3];
    const float* sb = (const float*)d_in[4];
    float* out = (float*)d_out;

    const int B   = in_sizes[0] / (512 * 784);
    const int nX1 = B * 8;                 // one block per (b,g) group
    const int nX0 = B * 16;                // B*8*32 channel-waves / 16 per block

    fused_sgate_onepass<<<nX1 + nX0, 1024, 0, stream>>>(
        (const f32x4*)x, cw, cb, sw, sb, (f32x4*)out, nX1);
}